// Round 17
// baseline (698.171 us; speedup 1.0000x reference)
//
#include <hip/hip_runtime.h>
#include <math.h>

#define NND 100000
#define TT 24
#define FI 16
#define HD 128
#define GD 384   // 3*HD
#define OD 64
#define NE 1600000

typedef __bf16 bf16x8 __attribute__((ext_vector_type(8)));
typedef float f32x4 __attribute__((ext_vector_type(4)));
typedef unsigned short u16;
typedef unsigned int u32;

#define S_RZ (-1.44269504f)   // -log2(e): sigmoid via rcp(1+exp2(s*a))
#define S_N  (-2.88539008f)   // -2*log2(e): tanh via 2*rcp(1+exp2(s*a))-1

__device__ __forceinline__ u16 f2b(float f) {
    u32 u = __float_as_uint(f);
    u32 r = (u + 0x7FFFu + ((u >> 16) & 1u)) >> 16;
    return (u16)r;
}
__device__ __forceinline__ u32 cvtpk(float lo, float hi) {
    u32 r;
    asm("v_cvt_pk_bf16_f32 %0, %1, %2" : "=v"(r) : "v"(lo), "v"(hi));
    return r;
}
__device__ __forceinline__ float b2f(u16 v) {
    return __uint_as_float((u32)v << 16);
}

// ---------------- fused prologue: cvt_x | pack_w | 4x pack_gemm | count ----------------
__device__ __forceinline__ void pack_gemm_dev(const float* __restrict__ W,
                                              u16* __restrict__ F, int id) {
    int lane = id & 63, fs = id >> 6;
    int s = fs & 3, tile = fs >> 2;
    int row = tile * 16 + (lane & 15);
    int k0 = s * 32 + (lane >> 4) * 8;
    const float* src = W + (size_t)row * HD + k0;
    u16 o[8];
#pragma unroll
    for (int e = 0; e < 8; ++e) o[e] = f2b(src[e]);
    u32* dst = (u32*)(F + (size_t)id * 8);
#pragma unroll
    for (int e = 0; e < 4; ++e) dst[e] = (u32)o[2 * e] | ((u32)o[2 * e + 1] << 16);
}

__global__ void prep_kernel(const float* __restrict__ x, u16* __restrict__ xb,
                            const float* __restrict__ Whh, const float* __restrict__ Wih,
                            const float* __restrict__ bih, const float* __restrict__ bhh,
                            u16* __restrict__ Ap, u16* __restrict__ Aip,
                            const float* __restrict__ W1l, u16* __restrict__ Pw1l,
                            const float* __restrict__ W1r, u16* __restrict__ Pw1r,
                            const float* __restrict__ W2l, u16* __restrict__ Pw2l,
                            const float* __restrict__ W2r, u16* __restrict__ Pw2r,
                            const int* __restrict__ dst, int* __restrict__ cnt) {
    const int bid = blockIdx.x;
    const int tid = threadIdx.x;
    if (bid < 18750) {
        size_t base = ((size_t)bid * 256 + tid) * 8;
        float4 a = *(const float4*)(x + base);
        float4 b = *(const float4*)(x + base + 4);
        u32 o0 = cvtpk(a.x, a.y), o1 = cvtpk(a.z, a.w);
        u32 o2 = cvtpk(b.x, b.y), o3 = cvtpk(b.z, b.w);
        *(uint4*)(xb + base) = make_uint4(o0, o1, o2, o3);
    } else if (bid < 18780) {
        int id = (bid - 18750) * 256 + tid;
        if (id < 6144) {
            int lane = id & 63, fs = id >> 6;
            int s = fs & 3, gt = fs >> 2;
            int row = gt * 16 + (lane & 15);
            float sc = (row < 2 * HD) ? S_RZ : S_N;
            int k0 = s * 32 + (lane >> 4) * 8;
            const float* src = Whh + (size_t)row * HD + k0;
            u16 o[8];
#pragma unroll
            for (int e = 0; e < 8; ++e) o[e] = f2b(src[e] * sc);
            u32* dp = (u32*)(Ap + (size_t)id * 8);
#pragma unroll
            for (int e = 0; e < 4; ++e) dp[e] = (u32)o[2 * e] | ((u32)o[2 * e + 1] << 16);
        } else if (id < 7680) {
            int id2 = id - 6144;
            int lane = id2 & 63, gt = id2 >> 6;
            int row = gt * 16 + (lane & 15);
            float sc = (row < 2 * HD) ? S_RZ : S_N;
            int g = lane >> 4;
            u16 o[8] = {0, 0, 0, 0, 0, 0, 0, 0};
            if (g < 2) {
                const float* src = Wih + (size_t)row * FI + g * 8;
#pragma unroll
                for (int e = 0; e < 8; ++e) o[e] = f2b(src[e] * sc);
            } else if (g == 2) {
                float bias = (row < 2 * HD) ? (bih[row] + bhh[row]) : bih[row];
                o[0] = f2b(bias * sc);
            }
            u32* dp = (u32*)(Aip + (size_t)id2 * 8);
#pragma unroll
            for (int e = 0; e < 4; ++e) dp[e] = (u32)o[2 * e] | ((u32)o[2 * e + 1] << 16);
        }
    } else if (bid < 18788) {
        pack_gemm_dev(W1l, Pw1l, (bid - 18780) * 256 + tid);
    } else if (bid < 18796) {
        pack_gemm_dev(W1r, Pw1r, (bid - 18788) * 256 + tid);
    } else if (bid < 18800) {
        pack_gemm_dev(W2l, Pw2l, (bid - 18796) * 256 + tid);
    } else if (bid < 18804) {
        pack_gemm_dev(W2r, Pw2r, (bid - 18800) * 256 + tid);
    } else {
        int e = (bid - 18804) * 256 + tid;
        if (e < NE) atomicAdd(&cnt[dst[e]], 1);
    }
}

// swizzled LDS index (u16 units): row stride 128, XOR bank swizzle
__device__ __forceinline__ int hidx(int row, int col) {
    return row * 128 + (col ^ ((row & 7) << 3));
}

// ---------------- GRU via MFMA + fused layer-1 dual projection epilogue ----------------
// R16 config + two changes:
//  (a) Ah s=3 slice lives in thread-private LDS (24 regs -> LDS; re-read per-m
//      as conflict-free ds_read_b128) to clear the residual HBM scratch spill.
//  (b) n-gate accumulator seeded with bnh4 via the MFMA C operand (saves adds).
__global__ __launch_bounds__(512, 4) void gru_mfma_kernel(
    const u16* __restrict__ xb,       // [N][T][16] bf16
    const u16* __restrict__ Ap,       // GRU Whh frags (scaled)
    const u16* __restrict__ Aip,      // GRU Wih' frags (scaled, bias k=16)
    const float* __restrict__ bhh,
    const u16* __restrict__ Wl,       // W1l frags
    const u16* __restrict__ Wr,       // W1r frags
    const float* __restrict__ b1,
    u16* __restrict__ P16,            // [N][128] bf16  = h@W1l^T
    u16* __restrict__ q16)            // [N][128] bf16  = h@W1r^T + b1 + h
{
    __shared__ u16 hb0[64 * 128];
    __shared__ u16 hb1[64 * 128];
    __shared__ u16 wl3[3 * 512 * 8];   // per-thread Ah s=3 slice (LDS "spill")

    const int tid = threadIdx.x;
    const int w = tid >> 6, lane = tid & 63;
    const int l15 = lane & 15, g = lane >> 4;
    const int gbase = blockIdx.x * 64;
    const int j0 = w * 16 + g * 4;

    for (int i = tid; i < 64 * 128 / 2; i += 512) ((u32*)hb0)[i] = 0u;

    bf16x8 Ah[3][3], Ai[3];
#pragma unroll
    for (int a = 0; a < 3; ++a) {
        int gt = w + a * 8;
#pragma unroll
        for (int s = 0; s < 3; ++s)
            Ah[a][s] = *(const bf16x8*)(Ap + ((size_t)(gt * 4 + s) * 64 + lane) * 8);
        bf16x8 t3 = *(const bf16x8*)(Ap + ((size_t)(gt * 4 + 3) * 64 + lane) * 8);
        *(bf16x8*)&wl3[(a * 512 + tid) * 8] = t3;
        Ai[a] = *(const bf16x8*)(Aip + ((size_t)(w + a * 8) * 64 + lane) * 8);
    }

    f32x4 bnh4 = *(const f32x4*)(bhh + 256 + j0);
#pragma unroll
    for (int r = 0; r < 4; ++r) bnh4[r] *= S_N;

    const f32x4 fz = {0.f, 0.f, 0.f, 0.f};
    bf16x8 xdef;
    {
        uint4 u = make_uint4(0u, 0u, 0u, 0u);
        if (g == 2) u.x = 0x3F80u;
        *(uint4*)&xdef = u;
    }

    f32x4 hreg[4];
#pragma unroll
    for (int m = 0; m < 4; ++m) hreg[m] = fz;

    int nd0 = gbase + l15;
    const u16* xbase = xb + (size_t)(nd0 < NND ? nd0 : NND - 1) * (TT * FI) + g * 8;

    __syncthreads();

    auto dostep = [&](int t, const u16* __restrict__ rb, u16* __restrict__ wb) {
#pragma unroll
        for (int m = 0; m < 4; ++m) {
            bf16x8 xf = xdef;
            if (g < 2) {
                int nd = gbase + m * 16 + l15;
                const u16* xp = (nd < NND) ? (xbase + m * 16 * (TT * FI)) : (xbase);
                xf = *(const bf16x8*)(xp + t * FI);
            }

            const int row = m * 16 + l15;
            f32x4 a0, a1, a2, ai;
            {
                bf16x8 b = *(const bf16x8*)&rb[hidx(row, g * 8)];
                a0 = __builtin_amdgcn_mfma_f32_16x16x32_bf16(Ah[0][0], b, fz, 0, 0, 0);
                a1 = __builtin_amdgcn_mfma_f32_16x16x32_bf16(Ah[1][0], b, fz, 0, 0, 0);
                a2 = __builtin_amdgcn_mfma_f32_16x16x32_bf16(Ah[2][0], b, bnh4, 0, 0, 0);
            }
#pragma unroll
            for (int s = 1; s < 3; ++s) {
                bf16x8 b = *(const bf16x8*)&rb[hidx(row, s * 32 + g * 8)];
                a0 = __builtin_amdgcn_mfma_f32_16x16x32_bf16(Ah[0][s], b, a0, 0, 0, 0);
                a1 = __builtin_amdgcn_mfma_f32_16x16x32_bf16(Ah[1][s], b, a1, 0, 0, 0);
                a2 = __builtin_amdgcn_mfma_f32_16x16x32_bf16(Ah[2][s], b, a2, 0, 0, 0);
            }
            {   // s = 3: weights re-read from LDS (short live range)
                bf16x8 b = *(const bf16x8*)&rb[hidx(row, 96 + g * 8)];
                bf16x8 w0 = *(const bf16x8*)&wl3[(0 * 512 + tid) * 8];
                a0 = __builtin_amdgcn_mfma_f32_16x16x32_bf16(w0, b, a0, 0, 0, 0);
                bf16x8 w1 = *(const bf16x8*)&wl3[(1 * 512 + tid) * 8];
                a1 = __builtin_amdgcn_mfma_f32_16x16x32_bf16(w1, b, a1, 0, 0, 0);
                bf16x8 w2 = *(const bf16x8*)&wl3[(2 * 512 + tid) * 8];
                a2 = __builtin_amdgcn_mfma_f32_16x16x32_bf16(w2, b, a2, 0, 0, 0);
            }
            a0 = __builtin_amdgcn_mfma_f32_16x16x32_bf16(Ai[0], xf, a0, 0, 0, 0);
            a1 = __builtin_amdgcn_mfma_f32_16x16x32_bf16(Ai[1], xf, a1, 0, 0, 0);
            ai = __builtin_amdgcn_mfma_f32_16x16x32_bf16(Ai[2], xf, fz, 0, 0, 0);

#pragma unroll
            for (int r = 0; r < 4; ++r) {
                float rr = __builtin_amdgcn_rcpf(1.0f + __builtin_amdgcn_exp2f(a0[r]));
                float zz = __builtin_amdgcn_rcpf(1.0f + __builtin_amdgcn_exp2f(a1[r]));
                float na = ai[r] + rr * a2[r];     // bnh folded into a2 seed
                float nn = 2.0f * __builtin_amdgcn_rcpf(1.0f + __builtin_amdgcn_exp2f(na)) - 1.0f;
                float h = nn + zz * (hreg[m][r] - nn);
                hreg[m][r] = h;
            }
            u32 p0 = cvtpk(hreg[m][0], hreg[m][1]);
            u32 p1 = cvtpk(hreg[m][2], hreg[m][3]);
            *(uint2*)&wb[hidx(row, j0)] = make_uint2(p0, p1);
        }
        __syncthreads();
    };

#pragma unroll 1
    for (int tt = 0; tt < TT; tt += 2) {
        dostep(tt, hb0, hb1);
        dostep(tt + 1, hb1, hb0);
    }
    // final h (bf16, swizzled) now lives in hb0; f32 copy in hreg.

    // ---- fused layer-1 dual projection ----
    bf16x8 Al[4], Ar[4];
#pragma unroll
    for (int s = 0; s < 4; ++s) {
        Al[s] = *(const bf16x8*)(Wl + ((size_t)(w * 4 + s) * 64 + lane) * 8);
        Ar[s] = *(const bf16x8*)(Wr + ((size_t)(w * 4 + s) * 64 + lane) * 8);
    }
    f32x4 bq = *(const f32x4*)(b1 + j0);

#pragma unroll
    for (int m = 0; m < 4; ++m) {
        f32x4 ap = fz, aq = fz;
#pragma unroll
        for (int s = 0; s < 4; ++s) {
            bf16x8 b = *(const bf16x8*)&hb0[hidx(m * 16 + l15, s * 32 + g * 8)];
            ap = __builtin_amdgcn_mfma_f32_16x16x32_bf16(Al[s], b, ap, 0, 0, 0);
            aq = __builtin_amdgcn_mfma_f32_16x16x32_bf16(Ar[s], b, aq, 0, 0, 0);
        }
        int nd = gbase + m * 16 + l15;
        if (nd < NND) {
            u32 c0 = cvtpk(ap[0], ap[1]), c1 = cvtpk(ap[2], ap[3]);
            *(uint2*)(P16 + (size_t)nd * HD + j0) = make_uint2(c0, c1);
            f32x4 v = aq + bq + hreg[m];
            u32 q0 = cvtpk(v[0], v[1]), q1 = cvtpk(v[2], v[3]);
            *(uint2*)(q16 + (size_t)nd * HD + j0) = make_uint2(q0, q1);
        }
    }
}

// ---------------- CSR scan ----------------
__global__ void blocksum_kernel(const int* __restrict__ cnt, int* __restrict__ bsum) {
    __shared__ int sh[256];
    int b = blockIdx.x, t = threadIdx.x;
    int base = b * 1024;
    int s = 0;
    for (int i = t; i < 1024; i += 256) {
        int idx = base + i;
        s += (idx < NND) ? cnt[idx] : 0;
    }
    sh[t] = s; __syncthreads();
    for (int o = 128; o > 0; o >>= 1) { if (t < o) sh[t] += sh[t + o]; __syncthreads(); }
    if (t == 0) bsum[b] = sh[0];
}

__global__ void scanbsum_kernel(int* __restrict__ bsum, int nb, int* __restrict__ rowptr) {
    if (threadIdx.x == 0 && blockIdx.x == 0) {
        int acc = 0;
        for (int i = 0; i < nb; ++i) { int v = bsum[i]; bsum[i] = acc; acc += v; }
        rowptr[NND] = NE;
    }
}

__global__ void scan_kernel(const int* __restrict__ cnt, const int* __restrict__ bsum,
                            int* __restrict__ rowptr) {
    __shared__ int sh[256];
    int b = blockIdx.x, t = threadIdx.x;
    int base = b * 1024;
    int v[4], loc = 0;
#pragma unroll
    for (int j = 0; j < 4; ++j) {
        int idx = base + t * 4 + j;
        v[j] = (idx < NND) ? cnt[idx] : 0;
        loc += v[j];
    }
    sh[t] = loc; __syncthreads();
    for (int o = 1; o < 256; o <<= 1) {
        int x = (t >= o) ? sh[t - o] : 0;
        __syncthreads();
        sh[t] += x;
        __syncthreads();
    }
    int acc = bsum[b] + sh[t] - loc;
#pragma unroll
    for (int j = 0; j < 4; ++j) {
        int idx = base + t * 4 + j;
        if (idx < NND) rowptr[idx] = acc;
        acc += v[j];
    }
}

// consumes cnt (counts -> 0); no separate fill array needed
__global__ void fill_kernel(const int* __restrict__ src, const int* __restrict__ dst,
                            const int* __restrict__ rowptr, int* __restrict__ cnt,
                            int* __restrict__ csr) {
    int e = blockIdx.x * 256 + threadIdx.x;
    if (e >= NE) return;
    int d = dst[e];
    int off = atomicSub(&cnt[d], 1) - 1;
    csr[rowptr[d] + off] = src[e];
}

// ---------------- fused gather (layer1 mean+relu) + layer-2 dual projection ----------------
__global__ __launch_bounds__(512) void gather_proj_kernel(
    const u16* __restrict__ P16,     // [N][128] bf16 messages
    const int* __restrict__ rowptr, const int* __restrict__ csr,
    const u16* __restrict__ q16,     // [N][128] bf16 self-path
    const u16* __restrict__ W2l, const u16* __restrict__ W2r,
    const float* __restrict__ b2,
    u16* __restrict__ P2,            // [N][64] bf16
    float* __restrict__ q2)          // [N][64] f32
{
    __shared__ u16 xs[64 * 128];

    const int tid = threadIdx.x;
    const int w = tid >> 6, lane = tid & 63;
    const int l15 = lane & 15, g = lane >> 4;
    const int gbase = blockIdx.x * 64;
    const f32x4 fz = {0.f, 0.f, 0.f, 0.f};

    // phase 1: each wave gathers 8 nodes; 8-deep load batching for MLP
#pragma unroll 1
    for (int i = 0; i < 8; ++i) {
        int nloc = w * 8 + i;
        int n = gbase + nloc;
        u32 gv = 0u;
        if (n < NND) {
            int beg = rowptr[n], end = rowptr[n + 1];
            float ax = 0.f, ay = 0.f;
            for (int cb = beg; cb < end; cb += 64) {
                int myi = (cb + lane < end) ? csr[cb + lane] : 0;
                int nn = min(end - cb, 64);
                int ii = 0;
                for (; ii + 8 <= nn; ii += 8) {
                    u32 p[8];
#pragma unroll
                    for (int u = 0; u < 8; ++u) {
                        int s = __shfl(myi, ii + u);
                        p[u] = *(const u32*)(P16 + (size_t)s * HD + lane * 2);
                    }
#pragma unroll
                    for (int u = 0; u < 8; ++u) {
                        ax += b2f((u16)p[u]); ay += b2f((u16)(p[u] >> 16));
                    }
                }
                for (; ii < nn; ++ii) {
                    int s = __shfl(myi, ii);
                    u32 pv = *(const u32*)(P16 + (size_t)s * HD + lane * 2);
                    ax += b2f((u16)pv); ay += b2f((u16)(pv >> 16));
                }
            }
            int deg = end - beg;
            float inv = 1.0f / (float)(deg > 0 ? deg : 1);
            u32 qv = *(const u32*)(q16 + (size_t)n * HD + lane * 2);
            float qx = b2f((u16)qv), qy = b2f((u16)(qv >> 16));
            gv = cvtpk(fmaxf(ax * inv + qx, 0.f), fmaxf(ay * inv + qy, 0.f));
        }
        *(u32*)&xs[hidx(nloc, lane * 2)] = gv;
    }
    __syncthreads();

    // phase 2: M=64 dual projection (waves 0-3 -> P2, 4-7 -> Q2)
    const int tile = w & 3;
    const bool isQ = (w >= 4);
    const u16* Wsel = isQ ? W2r : W2l;
    bf16x8 A[4];
#pragma unroll
    for (int s = 0; s < 4; ++s)
        A[s] = *(const bf16x8*)(Wsel + ((size_t)(tile * 4 + s) * 64 + lane) * 8);
    const int f0 = tile * 16 + g * 4;
    f32x4 bq = *(const f32x4*)(b2 + f0);

#pragma unroll
    for (int m = 0; m < 4; ++m) {
        bf16x8 b[4];
#pragma unroll
        for (int s = 0; s < 4; ++s)
            b[s] = *(const bf16x8*)&xs[hidx(m * 16 + l15, s * 32 + g * 8)];
        f32x4 a = fz;
#pragma unroll
        for (int s = 0; s < 4; ++s)
            a = __builtin_amdgcn_mfma_f32_16x16x32_bf16(A[s], b[s], a, 0, 0, 0);
        int nd = gbase + m * 16 + l15;
        if (nd < NND) {
            if (isQ) {
                f32x4 v = a + bq;
                *(f32x4*)(q2 + (size_t)nd * OD + f0) = v;
            } else {
                u32 c0 = cvtpk(a[0], a[1]), c1 = cvtpk(a[2], a[3]);
                *(uint2*)(P2 + (size_t)nd * OD + f0) = make_uint2(c0, c1);
            }
        }
    }
}

// ---------------- final gather (layer2 mean), 8-deep load batching ----------------
__global__ __launch_bounds__(256) void gather2_kernel(
    const u16* __restrict__ P2,      // [N][64] bf16
    const int* __restrict__ rowptr, const int* __restrict__ csr,
    const float* __restrict__ q2,    // [N][64] f32
    float* __restrict__ outp)        // [N][64] f32
{
    int n = ((blockIdx.x * 256 + threadIdx.x) >> 6);
    if (n >= NND) return;
    int lane = threadIdx.x & 63;
    int beg = rowptr[n], end = rowptr[n + 1];

    float a = 0.f;
    for (int cb = beg; cb < end; cb += 64) {
        int myi = (cb + lane < end) ? csr[cb + lane] : 0;
        int nn = min(end - cb, 64);
        int i = 0;
        for (; i + 8 <= nn; i += 8) {
            u16 v[8];
#pragma unroll
            for (int u = 0; u < 8; ++u) {
                int s = __shfl(myi, i + u);
                v[u] = P2[(size_t)s * OD + lane];
            }
#pragma unroll
            for (int u = 0; u < 8; ++u) a += b2f(v[u]);
        }
        for (; i < nn; ++i) {
            int s = __shfl(myi, i);
            a += b2f(P2[(size_t)s * OD + lane]);
        }
    }
    int deg = end - beg;
    float inv = 1.0f / (float)(deg > 0 ? deg : 1);
    outp[(size_t)n * OD + lane] = a * inv + q2[(size_t)n * OD + lane];
}

// ---------------- launch ----------------
extern "C" void kernel_launch(void* const* d_in, const int* in_sizes, int n_in,
                              void* d_out, int out_size, void* d_ws, size_t ws_size,
                              hipStream_t stream) {
    const float* x   = (const float*)d_in[0];
    const int*   edg = (const int*)d_in[1];
    const int*   src = edg;
    const int*   dst = edg + NE;
    const float* Wih = (const float*)d_in[2];
    const float* Whh = (const float*)d_in[3];
    const float* bih = (const float*)d_in[4];
    const float* bhh = (const float*)d_in[5];
    const float* W1l = (const float*)d_in[6];
    const float* b1  = (const float*)d_in[7];
    const float* W1r = (const float*)d_in[8];
    const float* W2l = (const float*)d_in[9];
    const float* b2  = (const float*)d_in[10];
    const float* W2r = (const float*)d_in[11];
    float* out = (float*)d_out;

    char* wsp = (char*)d_ws;
    auto alloc = [&](size_t nbytes) {
        char* p = wsp; wsp += (nbytes + 255) & ~(size_t)255; return p;
    };
    u16*   Ap    = (u16*)alloc((size_t)6144 * 8 * 2);
    u16*   Aip   = (u16*)alloc((size_t)1536 * 8 * 2);
    u16*   Pw1l  = (u16*)alloc((size_t)2048 * 8 * 2);
    u16*   Pw1r  = (u16*)alloc((size_t)2048 * 8 * 2);
    u16*   Pw2l  = (u16*)alloc((size_t)1024 * 8 * 2);
    u16*   Pw2r  = (u16*)alloc((size_t)1024 * 8 * 2);
    int*   cnt   = (int*)alloc((size_t)NND * 4);
    int*   rowp  = (int*)alloc((size_t)(NND + 1) * 4);
    int*   bsum  = (int*)alloc((size_t)128 * 4);
    int*   csr   = (int*)alloc((size_t)NE * 4);
    u16*   xb    = (u16*)alloc((size_t)NND * TT * FI * 2);
    u16*   q16   = (u16*)alloc((size_t)NND * HD * 2);
    u16*   P16   = (u16*)alloc((size_t)NND * HD * 2);
    u16*   P2    = (u16*)alloc((size_t)NND * OD * 2);
    float* q2    = (float*)alloc((size_t)NND * OD * 4);

    const int NB_SCAN = (NND + 1023) / 1024;

    hipMemsetAsync(cnt, 0, (size_t)NND * 4, stream);

    // fused prologue: cvt_x + all weight packing + edge count, one launch
    prep_kernel<<<25054, 256, 0, stream>>>(x, xb, Whh, Wih, bih, bhh, Ap, Aip,
                                           W1l, Pw1l, W1r, Pw1r, W2l, Pw2l, W2r, Pw2r,
                                           dst, cnt);

    // CSR scan + fill
    blocksum_kernel<<<NB_SCAN, 256, 0, stream>>>(cnt, bsum);
    scanbsum_kernel<<<1, 64, 0, stream>>>(bsum, NB_SCAN, rowp);
    scan_kernel<<<NB_SCAN, 256, 0, stream>>>(cnt, bsum, rowp);
    fill_kernel<<<(NE + 255) / 256, 256, 0, stream>>>(src, dst, rowp, cnt, csr);

    // GRU + fused layer-1 projection -> P16 (bf16), q16 (bf16, bias+residual)
    const int nblk = (NND + 63) / 64;
    gru_mfma_kernel<<<nblk, 512, 0, stream>>>(xb, Ap, Aip, bhh, Pw1l, Pw1r, b1, P16, q16);

    // gather layer-1 (+relu) fused with layer-2 projection -> P2, q2
    gather_proj_kernel<<<nblk, 512, 0, stream>>>(P16, rowp, csr, q16, Pw2l, Pw2r, b2, P2, q2);

    // final mean-gather -> out
    gather2_kernel<<<(NND * 64 + 255) / 256, 256, 0, stream>>>(P2, rowp, csr, q2, out);
}

// Round 18
// 692.437 us; speedup vs baseline: 1.0083x; 1.0083x over previous
//
#include <hip/hip_runtime.h>
#include <math.h>

#define NND 100000
#define TT 24
#define FI 16
#define HD 128
#define GD 384   // 3*HD
#define OD 64
#define NE 1600000

typedef __bf16 bf16x8 __attribute__((ext_vector_type(8)));
typedef float f32x4 __attribute__((ext_vector_type(4)));
typedef unsigned short u16;
typedef unsigned int u32;

#define S_RZ (-1.44269504f)   // -log2(e): sigmoid via rcp(1+exp2(s*a))
#define S_N  (-2.88539008f)   // -2*log2(e): tanh via 2*rcp(1+exp2(s*a))-1

__device__ __forceinline__ u16 f2b(float f) {
    u32 u = __float_as_uint(f);
    u32 r = (u + 0x7FFFu + ((u >> 16) & 1u)) >> 16;
    return (u16)r;
}
__device__ __forceinline__ u32 cvtpk(float lo, float hi) {
    u32 r;
    asm("v_cvt_pk_bf16_f32 %0, %1, %2" : "=v"(r) : "v"(lo), "v"(hi));
    return r;
}
__device__ __forceinline__ float b2f(u16 v) {
    return __uint_as_float((u32)v << 16);
}

// ---------------- fused prologue: cvt_x | pack_w | 4x pack_gemm | count ----------------
__device__ __forceinline__ void pack_gemm_dev(const float* __restrict__ W,
                                              u16* __restrict__ F, int id) {
    int lane = id & 63, fs = id >> 6;
    int s = fs & 3, tile = fs >> 2;
    int row = tile * 16 + (lane & 15);
    int k0 = s * 32 + (lane >> 4) * 8;
    const float* src = W + (size_t)row * HD + k0;
    u16 o[8];
#pragma unroll
    for (int e = 0; e < 8; ++e) o[e] = f2b(src[e]);
    u32* dst = (u32*)(F + (size_t)id * 8);
#pragma unroll
    for (int e = 0; e < 4; ++e) dst[e] = (u32)o[2 * e] | ((u32)o[2 * e + 1] << 16);
}

// grid = 25054 blocks x 256
//   [0,18750)      cvt_x        (38.4M f32 -> bf16, 8/thread)
//   [18750,18780)  pack_w       (GRU frags, 7680 ids)
//   [18780,18788)  pack W1l     (2048 ids)
//   [18788,18796)  pack W1r
//   [18796,18800)  pack W2l     (1024 ids)
//   [18800,18804)  pack W2r
//   [18804,25054)  count        (1.6M edges)
__global__ void prep_kernel(const float* __restrict__ x, u16* __restrict__ xb,
                            const float* __restrict__ Whh, const float* __restrict__ Wih,
                            const float* __restrict__ bih, const float* __restrict__ bhh,
                            u16* __restrict__ Ap, u16* __restrict__ Aip,
                            const float* __restrict__ W1l, u16* __restrict__ Pw1l,
                            const float* __restrict__ W1r, u16* __restrict__ Pw1r,
                            const float* __restrict__ W2l, u16* __restrict__ Pw2l,
                            const float* __restrict__ W2r, u16* __restrict__ Pw2r,
                            const int* __restrict__ dst, int* __restrict__ cnt) {
    const int bid = blockIdx.x;
    const int tid = threadIdx.x;
    if (bid < 18750) {
        size_t base = ((size_t)bid * 256 + tid) * 8;
        float4 a = *(const float4*)(x + base);
        float4 b = *(const float4*)(x + base + 4);
        u32 o0 = cvtpk(a.x, a.y), o1 = cvtpk(a.z, a.w);
        u32 o2 = cvtpk(b.x, b.y), o3 = cvtpk(b.z, b.w);
        *(uint4*)(xb + base) = make_uint4(o0, o1, o2, o3);
    } else if (bid < 18780) {
        int id = (bid - 18750) * 256 + tid;
        if (id < 6144) {
            int lane = id & 63, fs = id >> 6;
            int s = fs & 3, gt = fs >> 2;
            int row = gt * 16 + (lane & 15);
            float sc = (row < 2 * HD) ? S_RZ : S_N;
            int k0 = s * 32 + (lane >> 4) * 8;
            const float* src = Whh + (size_t)row * HD + k0;
            u16 o[8];
#pragma unroll
            for (int e = 0; e < 8; ++e) o[e] = f2b(src[e] * sc);
            u32* dp = (u32*)(Ap + (size_t)id * 8);
#pragma unroll
            for (int e = 0; e < 4; ++e) dp[e] = (u32)o[2 * e] | ((u32)o[2 * e + 1] << 16);
        } else if (id < 7680) {
            int id2 = id - 6144;
            int lane = id2 & 63, gt = id2 >> 6;
            int row = gt * 16 + (lane & 15);
            float sc = (row < 2 * HD) ? S_RZ : S_N;
            int g = lane >> 4;
            u16 o[8] = {0, 0, 0, 0, 0, 0, 0, 0};
            if (g < 2) {
                const float* src = Wih + (size_t)row * FI + g * 8;
#pragma unroll
                for (int e = 0; e < 8; ++e) o[e] = f2b(src[e] * sc);
            } else if (g == 2) {
                float bias = (row < 2 * HD) ? (bih[row] + bhh[row]) : bih[row];
                o[0] = f2b(bias * sc);
            }
            u32* dp = (u32*)(Aip + (size_t)id2 * 8);
#pragma unroll
            for (int e = 0; e < 4; ++e) dp[e] = (u32)o[2 * e] | ((u32)o[2 * e + 1] << 16);
        }
    } else if (bid < 18788) {
        pack_gemm_dev(W1l, Pw1l, (bid - 18780) * 256 + tid);
    } else if (bid < 18796) {
        pack_gemm_dev(W1r, Pw1r, (bid - 18788) * 256 + tid);
    } else if (bid < 18800) {
        pack_gemm_dev(W2l, Pw2l, (bid - 18796) * 256 + tid);
    } else if (bid < 18804) {
        pack_gemm_dev(W2r, Pw2r, (bid - 18800) * 256 + tid);
    } else {
        int e = (bid - 18804) * 256 + tid;
        if (e < NE) atomicAdd(&cnt[dst[e]], 1);
    }
}

// swizzled LDS index (u16 units): row stride 128, XOR bank swizzle
__device__ __forceinline__ int hidx(int row, int col) {
    return row * 128 + (col ^ ((row & 7) << 3));
}

// ---------------- GRU via MFMA + fused layer-1 dual projection epilogue ----------------
// R12/R16 verified configuration (best: gru ~420 us, 2 blocks/CU, occ 38%).
__global__ __launch_bounds__(512, 4) void gru_mfma_kernel(
    const u16* __restrict__ xb,       // [N][T][16] bf16
    const u16* __restrict__ Ap,       // GRU Whh frags (scaled)
    const u16* __restrict__ Aip,      // GRU Wih' frags (scaled, bias k=16)
    const float* __restrict__ bhh,
    const u16* __restrict__ Wl,       // W1l frags
    const u16* __restrict__ Wr,       // W1r frags
    const float* __restrict__ b1,
    u16* __restrict__ P16,            // [N][128] bf16  = h@W1l^T
    u16* __restrict__ q16)            // [N][128] bf16  = h@W1r^T + b1 + h
{
    __shared__ u16 hb0[64 * 128];
    __shared__ u16 hb1[64 * 128];

    const int tid = threadIdx.x;
    const int w = tid >> 6, lane = tid & 63;
    const int l15 = lane & 15, g = lane >> 4;
    const int gbase = blockIdx.x * 64;
    const int j0 = w * 16 + g * 4;

    for (int i = tid; i < 64 * 128 / 2; i += 512) ((u32*)hb0)[i] = 0u;

    bf16x8 Ah[3][4], Ai[3];
#pragma unroll
    for (int a = 0; a < 3; ++a) {
        int gt = w + a * 8;
#pragma unroll
        for (int s = 0; s < 4; ++s)
            Ah[a][s] = *(const bf16x8*)(Ap + ((size_t)(gt * 4 + s) * 64 + lane) * 8);
        Ai[a] = *(const bf16x8*)(Aip + ((size_t)(w + a * 8) * 64 + lane) * 8);
    }

    f32x4 bnh4 = *(const f32x4*)(bhh + 256 + j0);
#pragma unroll
    for (int r = 0; r < 4; ++r) bnh4[r] *= S_N;

    const f32x4 fz = {0.f, 0.f, 0.f, 0.f};
    bf16x8 xdef;
    {
        uint4 u = make_uint4(0u, 0u, 0u, 0u);
        if (g == 2) u.x = 0x3F80u;
        *(uint4*)&xdef = u;
    }

    f32x4 hreg[4];
#pragma unroll
    for (int m = 0; m < 4; ++m) hreg[m] = fz;

    int nd0 = gbase + l15;
    const u16* xbase = xb + (size_t)(nd0 < NND ? nd0 : NND - 1) * (TT * FI) + g * 8;

    __syncthreads();

    auto dostep = [&](int t, const u16* __restrict__ rb, u16* __restrict__ wb) {
#pragma unroll
        for (int m = 0; m < 4; ++m) {
            bf16x8 xf = xdef;
            if (g < 2) {
                int nd = gbase + m * 16 + l15;
                const u16* xp = (nd < NND) ? (xbase + m * 16 * (TT * FI)) : (xbase);
                xf = *(const bf16x8*)(xp + t * FI);
            }

            const int row = m * 16 + l15;
            f32x4 a0, a1, a2, ai;
            {
                bf16x8 b = *(const bf16x8*)&rb[hidx(row, g * 8)];
                a0 = __builtin_amdgcn_mfma_f32_16x16x32_bf16(Ah[0][0], b, fz, 0, 0, 0);
                a1 = __builtin_amdgcn_mfma_f32_16x16x32_bf16(Ah[1][0], b, fz, 0, 0, 0);
                a2 = __builtin_amdgcn_mfma_f32_16x16x32_bf16(Ah[2][0], b, fz, 0, 0, 0);
            }
#pragma unroll
            for (int s = 1; s < 4; ++s) {
                bf16x8 b = *(const bf16x8*)&rb[hidx(row, s * 32 + g * 8)];
                a0 = __builtin_amdgcn_mfma_f32_16x16x32_bf16(Ah[0][s], b, a0, 0, 0, 0);
                a1 = __builtin_amdgcn_mfma_f32_16x16x32_bf16(Ah[1][s], b, a1, 0, 0, 0);
                a2 = __builtin_amdgcn_mfma_f32_16x16x32_bf16(Ah[2][s], b, a2, 0, 0, 0);
            }
            a0 = __builtin_amdgcn_mfma_f32_16x16x32_bf16(Ai[0], xf, a0, 0, 0, 0);
            a1 = __builtin_amdgcn_mfma_f32_16x16x32_bf16(Ai[1], xf, a1, 0, 0, 0);
            ai = __builtin_amdgcn_mfma_f32_16x16x32_bf16(Ai[2], xf, fz, 0, 0, 0);

#pragma unroll
            for (int r = 0; r < 4; ++r) {
                float rr = __builtin_amdgcn_rcpf(1.0f + __builtin_amdgcn_exp2f(a0[r]));
                float zz = __builtin_amdgcn_rcpf(1.0f + __builtin_amdgcn_exp2f(a1[r]));
                float na = ai[r] + rr * (a2[r] + bnh4[r]);
                float nn = 2.0f * __builtin_amdgcn_rcpf(1.0f + __builtin_amdgcn_exp2f(na)) - 1.0f;
                float h = nn + zz * (hreg[m][r] - nn);
                hreg[m][r] = h;
            }
            u32 p0 = cvtpk(hreg[m][0], hreg[m][1]);
            u32 p1 = cvtpk(hreg[m][2], hreg[m][3]);
            *(uint2*)&wb[hidx(row, j0)] = make_uint2(p0, p1);
        }
        __syncthreads();
    };

#pragma unroll 1
    for (int tt = 0; tt < TT; tt += 2) {
        dostep(tt, hb0, hb1);
        dostep(tt + 1, hb1, hb0);
    }
    // final h (bf16, swizzled) now lives in hb0; f32 copy in hreg.

    // ---- fused layer-1 dual projection ----
    bf16x8 Al[4], Ar[4];
#pragma unroll
    for (int s = 0; s < 4; ++s) {
        Al[s] = *(const bf16x8*)(Wl + ((size_t)(w * 4 + s) * 64 + lane) * 8);
        Ar[s] = *(const bf16x8*)(Wr + ((size_t)(w * 4 + s) * 64 + lane) * 8);
    }
    f32x4 bq = *(const f32x4*)(b1 + j0);

#pragma unroll
    for (int m = 0; m < 4; ++m) {
        f32x4 ap = fz, aq = fz;
#pragma unroll
        for (int s = 0; s < 4; ++s) {
            bf16x8 b = *(const bf16x8*)&hb0[hidx(m * 16 + l15, s * 32 + g * 8)];
            ap = __builtin_amdgcn_mfma_f32_16x16x32_bf16(Al[s], b, ap, 0, 0, 0);
            aq = __builtin_amdgcn_mfma_f32_16x16x32_bf16(Ar[s], b, aq, 0, 0, 0);
        }
        int nd = gbase + m * 16 + l15;
        if (nd < NND) {
            u32 c0 = cvtpk(ap[0], ap[1]), c1 = cvtpk(ap[2], ap[3]);
            *(uint2*)(P16 + (size_t)nd * HD + j0) = make_uint2(c0, c1);
            f32x4 v = aq + bq + hreg[m];
            u32 q0 = cvtpk(v[0], v[1]), q1 = cvtpk(v[2], v[3]);
            *(uint2*)(q16 + (size_t)nd * HD + j0) = make_uint2(q0, q1);
        }
    }
}

// ---------------- CSR scan ----------------
__global__ void blocksum_kernel(const int* __restrict__ cnt, int* __restrict__ bsum) {
    __shared__ int sh[256];
    int b = blockIdx.x, t = threadIdx.x;
    int base = b * 1024;
    int s = 0;
    for (int i = t; i < 1024; i += 256) {
        int idx = base + i;
        s += (idx < NND) ? cnt[idx] : 0;
    }
    sh[t] = s; __syncthreads();
    for (int o = 128; o > 0; o >>= 1) { if (t < o) sh[t] += sh[t + o]; __syncthreads(); }
    if (t == 0) bsum[b] = sh[0];
}

__global__ void scanbsum_kernel(int* __restrict__ bsum, int nb, int* __restrict__ rowptr) {
    if (threadIdx.x == 0 && blockIdx.x == 0) {
        int acc = 0;
        for (int i = 0; i < nb; ++i) { int v = bsum[i]; bsum[i] = acc; acc += v; }
        rowptr[NND] = NE;
    }
}

__global__ void scan_kernel(const int* __restrict__ cnt, const int* __restrict__ bsum,
                            int* __restrict__ rowptr) {
    __shared__ int sh[256];
    int b = blockIdx.x, t = threadIdx.x;
    int base = b * 1024;
    int v[4], loc = 0;
#pragma unroll
    for (int j = 0; j < 4; ++j) {
        int idx = base + t * 4 + j;
        v[j] = (idx < NND) ? cnt[idx] : 0;
        loc += v[j];
    }
    sh[t] = loc; __syncthreads();
    for (int o = 1; o < 256; o <<= 1) {
        int x = (t >= o) ? sh[t - o] : 0;
        __syncthreads();
        sh[t] += x;
        __syncthreads();
    }
    int acc = bsum[b] + sh[t] - loc;
#pragma unroll
    for (int j = 0; j < 4; ++j) {
        int idx = base + t * 4 + j;
        if (idx < NND) rowptr[idx] = acc;
        acc += v[j];
    }
}

// consumes cnt (counts -> 0); no separate fill array needed
__global__ void fill_kernel(const int* __restrict__ src, const int* __restrict__ dst,
                            const int* __restrict__ rowptr, int* __restrict__ cnt,
                            int* __restrict__ csr) {
    int e = blockIdx.x * 256 + threadIdx.x;
    if (e >= NE) return;
    int d = dst[e];
    int off = atomicSub(&cnt[d], 1) - 1;
    csr[rowptr[d] + off] = src[e];
}

// ---------------- fused gather (layer1 mean+relu) + layer-2 dual projection ----------------
__global__ __launch_bounds__(512) void gather_proj_kernel(
    const u16* __restrict__ P16,     // [N][128] bf16 messages
    const int* __restrict__ rowptr, const int* __restrict__ csr,
    const u16* __restrict__ q16,     // [N][128] bf16 self-path
    const u16* __restrict__ W2l, const u16* __restrict__ W2r,
    const float* __restrict__ b2,
    u16* __restrict__ P2,            // [N][64] bf16
    float* __restrict__ q2)          // [N][64] f32
{
    __shared__ u16 xs[64 * 128];

    const int tid = threadIdx.x;
    const int w = tid >> 6, lane = tid & 63;
    const int l15 = lane & 15, g = lane >> 4;
    const int gbase = blockIdx.x * 64;
    const f32x4 fz = {0.f, 0.f, 0.f, 0.f};

    // phase 1: each wave gathers 8 nodes; 8-deep load batching for MLP
#pragma unroll 1
    for (int i = 0; i < 8; ++i) {
        int nloc = w * 8 + i;
        int n = gbase + nloc;
        u32 gv = 0u;
        if (n < NND) {
            int beg = rowptr[n], end = rowptr[n + 1];
            float ax = 0.f, ay = 0.f;
            for (int cb = beg; cb < end; cb += 64) {
                int myi = (cb + lane < end) ? csr[cb + lane] : 0;
                int nn = min(end - cb, 64);
                int ii = 0;
                for (; ii + 8 <= nn; ii += 8) {
                    u32 p[8];
#pragma unroll
                    for (int u = 0; u < 8; ++u) {
                        int s = __shfl(myi, ii + u);
                        p[u] = *(const u32*)(P16 + (size_t)s * HD + lane * 2);
                    }
#pragma unroll
                    for (int u = 0; u < 8; ++u) {
                        ax += b2f((u16)p[u]); ay += b2f((u16)(p[u] >> 16));
                    }
                }
                for (; ii < nn; ++ii) {
                    int s = __shfl(myi, ii);
                    u32 pv = *(const u32*)(P16 + (size_t)s * HD + lane * 2);
                    ax += b2f((u16)pv); ay += b2f((u16)(pv >> 16));
                }
            }
            int deg = end - beg;
            float inv = 1.0f / (float)(deg > 0 ? deg : 1);
            u32 qv = *(const u32*)(q16 + (size_t)n * HD + lane * 2);
            float qx = b2f((u16)qv), qy = b2f((u16)(qv >> 16));
            gv = cvtpk(fmaxf(ax * inv + qx, 0.f), fmaxf(ay * inv + qy, 0.f));
        }
        *(u32*)&xs[hidx(nloc, lane * 2)] = gv;
    }
    __syncthreads();

    // phase 2: M=64 dual projection (waves 0-3 -> P2, 4-7 -> Q2)
    const int tile = w & 3;
    const bool isQ = (w >= 4);
    const u16* Wsel = isQ ? W2r : W2l;
    bf16x8 A[4];
#pragma unroll
    for (int s = 0; s < 4; ++s)
        A[s] = *(const bf16x8*)(Wsel + ((size_t)(tile * 4 + s) * 64 + lane) * 8);
    const int f0 = tile * 16 + g * 4;
    f32x4 bq = *(const f32x4*)(b2 + f0);

#pragma unroll
    for (int m = 0; m < 4; ++m) {
        bf16x8 b[4];
#pragma unroll
        for (int s = 0; s < 4; ++s)
            b[s] = *(const bf16x8*)&xs[hidx(m * 16 + l15, s * 32 + g * 8)];
        f32x4 a = fz;
#pragma unroll
        for (int s = 0; s < 4; ++s)
            a = __builtin_amdgcn_mfma_f32_16x16x32_bf16(A[s], b[s], a, 0, 0, 0);
        int nd = gbase + m * 16 + l15;
        if (nd < NND) {
            if (isQ) {
                f32x4 v = a + bq;
                *(f32x4*)(q2 + (size_t)nd * OD + f0) = v;
            } else {
                u32 c0 = cvtpk(a[0], a[1]), c1 = cvtpk(a[2], a[3]);
                *(uint2*)(P2 + (size_t)nd * OD + f0) = make_uint2(c0, c1);
            }
        }
    }
}

// ---------------- final gather (layer2 mean), 8-deep load batching ----------------
__global__ __launch_bounds__(256) void gather2_kernel(
    const u16* __restrict__ P2,      // [N][64] bf16
    const int* __restrict__ rowptr, const int* __restrict__ csr,
    const float* __restrict__ q2,    // [N][64] f32
    float* __restrict__ outp)        // [N][64] f32
{
    int n = ((blockIdx.x * 256 + threadIdx.x) >> 6);
    if (n >= NND) return;
    int lane = threadIdx.x & 63;
    int beg = rowptr[n], end = rowptr[n + 1];

    float a = 0.f;
    for (int cb = beg; cb < end; cb += 64) {
        int myi = (cb + lane < end) ? csr[cb + lane] : 0;
        int nn = min(end - cb, 64);
        int i = 0;
        for (; i + 8 <= nn; i += 8) {
            u16 v[8];
#pragma unroll
            for (int u = 0; u < 8; ++u) {
                int s = __shfl(myi, i + u);
                v[u] = P2[(size_t)s * OD + lane];
            }
#pragma unroll
            for (int u = 0; u < 8; ++u) a += b2f(v[u]);
        }
        for (; i < nn; ++i) {
            int s = __shfl(myi, i);
            a += b2f(P2[(size_t)s * OD + lane]);
        }
    }
    int deg = end - beg;
    float inv = 1.0f / (float)(deg > 0 ? deg : 1);
    outp[(size_t)n * OD + lane] = a * inv + q2[(size_t)n * OD + lane];
}

// ---------------- launch ----------------
extern "C" void kernel_launch(void* const* d_in, const int* in_sizes, int n_in,
                              void* d_out, int out_size, void* d_ws, size_t ws_size,
                              hipStream_t stream) {
    const float* x   = (const float*)d_in[0];
    const int*   edg = (const int*)d_in[1];
    const int*   src = edg;
    const int*   dst = edg + NE;
    const float* Wih = (const float*)d_in[2];
    const float* Whh = (const float*)d_in[3];
    const float* bih = (const float*)d_in[4];
    const float* bhh = (const float*)d_in[5];
    const float* W1l = (const float*)d_in[6];
    const float* b1  = (const float*)d_in[7];
    const float* W1r = (const float*)d_in[8];
    const float* W2l = (const float*)d_in[9];
    const float* b2  = (const float*)d_in[10];
    const float* W2r = (const float*)d_in[11];
    float* out = (float*)d_out;

    char* wsp = (char*)d_ws;
    auto alloc = [&](size_t nbytes) {
        char* p = wsp; wsp += (nbytes + 255) & ~(size_t)255; return p;
    };
    u16*   Ap    = (u16*)alloc((size_t)6144 * 8 * 2);
    u16*   Aip   = (u16*)alloc((size_t)1536 * 8 * 2);
    u16*   Pw1l  = (u16*)alloc((size_t)2048 * 8 * 2);
    u16*   Pw1r  = (u16*)alloc((size_t)2048 * 8 * 2);
    u16*   Pw2l  = (u16*)alloc((size_t)1024 * 8 * 2);
    u16*   Pw2r  = (u16*)alloc((size_t)1024 * 8 * 2);
    int*   cnt   = (int*)alloc((size_t)NND * 4);
    int*   rowp  = (int*)alloc((size_t)(NND + 1) * 4);
    int*   bsum  = (int*)alloc((size_t)128 * 4);
    int*   csr   = (int*)alloc((size_t)NE * 4);
    u16*   xb    = (u16*)alloc((size_t)NND * TT * FI * 2);
    u16*   q16   = (u16*)alloc((size_t)NND * HD * 2);
    u16*   P16   = (u16*)alloc((size_t)NND * HD * 2);
    u16*   P2    = (u16*)alloc((size_t)NND * OD * 2);
    float* q2    = (float*)alloc((size_t)NND * OD * 4);

    const int NB_SCAN = (NND + 1023) / 1024;

    hipMemsetAsync(cnt, 0, (size_t)NND * 4, stream);

    // fused prologue: cvt_x + all weight packing + edge count, one launch
    prep_kernel<<<25054, 256, 0, stream>>>(x, xb, Whh, Wih, bih, bhh, Ap, Aip,
                                           W1l, Pw1l, W1r, Pw1r, W2l, Pw2l, W2r, Pw2r,
                                           dst, cnt);

    // CSR scan + fill
    blocksum_kernel<<<NB_SCAN, 256, 0, stream>>>(cnt, bsum);
    scanbsum_kernel<<<1, 64, 0, stream>>>(bsum, NB_SCAN, rowp);
    scan_kernel<<<NB_SCAN, 256, 0, stream>>>(cnt, bsum, rowp);
    fill_kernel<<<(NE + 255) / 256, 256, 0, stream>>>(src, dst, rowp, cnt, csr);

    // GRU + fused layer-1 projection -> P16 (bf16), q16 (bf16, bias+residual)
    const int nblk = (NND + 63) / 64;
    gru_mfma_kernel<<<nblk, 512, 0, stream>>>(xb, Ap, Aip, bhh, Pw1l, Pw1r, b1, P16, q16);

    // gather layer-1 (+relu) fused with layer-2 projection -> P2, q2
    gather_proj_kernel<<<nblk, 512, 0, stream>>>(P16, rowp, csr, q16, Pw2l, Pw2r, b2, P2, q2);

    // final mean-gather -> out
    gather2_kernel<<<(NND * 64 + 255) / 256, 256, 0, stream>>>(P2, rowp, csr, q2, out);
}